// Round 6
// baseline (329.922 us; speedup 1.0000x reference)
//
#include <hip/hip_runtime.h>
#include <math.h>

#define NGRAPH 256
#define NPG 64
#define NFEAT 64
#define HC 504
#define NLAY 4
#define EPER 1024
#define NTRIU 2016
#define DCAT 4032
#define HID1 1024
#define HID2 512

#define GCN_LDS (65536 + 73728 + 16384)   // cur + xwt + ahl = 155648 B

typedef __attribute__((ext_vector_type(8))) short bfrag8;   // 8 bf16 in 4 VGPRs
typedef __attribute__((ext_vector_type(4))) float f32x4;

struct __align__(8) us4 { unsigned short a, b, c, d; };

__device__ __forceinline__ unsigned short f2b(float f) {
    union { float f; unsigned u; } v; v.f = f;
    unsigned r = (v.u + 0x7fffu + ((v.u >> 16) & 1u)) >> 16;   // RNE
    return (unsigned short)r;
}
__device__ __forceinline__ float b2f(unsigned short h) {
    union { unsigned u; float f; } v; v.u = ((unsigned)h) << 16;
    return v.f;
}

// ---------------------------------------------------------------------------
// triu(64, k=1) flat-offset table: off[t] = iu*64 + ju
// ---------------------------------------------------------------------------
__global__ void triu_off(int* __restrict__ off)
{
    int i = threadIdx.x;
    if (i >= 63) return;
    int o = 63 * i - i * (i - 1) / 2;
    for (int j = i + 1; j < 64; ++j) { off[o] = i * 64 + j; ++o; }
}

// ---------------------------------------------------------------------------
// Weight transpose+convert (row layout): Wt[n][k] = bf16(W[k][n])
// ---------------------------------------------------------------------------
__global__ void convWt(const float* __restrict__ W, unsigned short* __restrict__ Wt,
                       int K, int N, int KP, long long sStride, long long dStride)
{
    W  += (size_t)blockIdx.z * sStride;
    Wt += (size_t)blockIdx.z * dStride;
    __shared__ float T[32][33];
    int k0 = blockIdx.y * 32, n0 = blockIdx.x * 32;
    int tx = threadIdx.x, ty = threadIdx.y;
#pragma unroll
    for (int j = 0; j < 32; j += 8) {
        int k = k0 + ty + j, n = n0 + tx;
        T[ty + j][tx] = (k < K && n < N) ? W[(size_t)k * N + n] : 0.f;
    }
    __syncthreads();
#pragma unroll
    for (int j = 0; j < 32; j += 8) {
        int n = n0 + ty + j, k = k0 + tx;
        Wt[(size_t)n * KP + k] = f2b(T[tx][ty + j]);
    }
}

// ---------------------------------------------------------------------------
// Weight convert to MFMA-fragment-major layout (for gcn_all):
// elem (n,k) -> ((n>>4)*(KL/32) + (k>>5))*512 + ((k>>3)&3)*128 + (n&15)*8 + (k&7)
// A wave's 16-col x 32-k B fragment is then 1KB contiguous (lane*8 within it).
// ---------------------------------------------------------------------------
__global__ void convW4(const float* __restrict__ W, unsigned short* __restrict__ W4,
                       int K, int N, int KL, long long sStride, long long dStride)
{
    W  += (size_t)blockIdx.z * sStride;
    W4 += (size_t)blockIdx.z * dStride;
    __shared__ float T[32][33];
    int k0 = blockIdx.y * 32, n0 = blockIdx.x * 32;
    int tx = threadIdx.x, ty = threadIdx.y;
#pragma unroll
    for (int j = 0; j < 32; j += 8) {
        int k = k0 + ty + j, n = n0 + tx;
        T[ty + j][tx] = (k < K && n < N) ? W[(size_t)k * N + n] : 0.f;
    }
    __syncthreads();
#pragma unroll
    for (int j = 0; j < 32; j += 8) {
        int n = n0 + ty + j, k = k0 + tx;
        int idx = ((n >> 4) * (KL >> 5) + (k >> 5)) * 512
                + (((k >> 3) & 3) << 7) + ((n & 15) << 3) + (k & 7);
        W4[idx] = f2b(T[tx][ty + j]);
    }
}

// ---------------------------------------------------------------------------
// One GCN layer for one graph (8 waves, wave wv owns cols wv*64..wv*64+63).
// Feature GEMM (cur @ W^T, W fragment-major from L2, depth-2 prefetch) ->
// xwt transpose (own cols) -> adjacency MFMA (split hi/lo from LDS) ->
// bias + pool + bf16 writeback to cur.
// ---------------------------------------------------------------------------
template<int KL>
__device__ __forceinline__ void gcn_layer(const unsigned short* __restrict__ W4,
                                          const float* __restrict__ bias,
                                          unsigned short* cur, unsigned short* xwt,
                                          const unsigned short* ahl,
                                          float* __restrict__ hsg,
                                          int wv, int lm, int lh)
{
    constexpr int KTS = KL >> 5;
    const int colw = wv << 6;
    const int kswz = (lm & 7) << 3;
    const int lane8 = ((lh << 4) + lm) << 3;   // lane * 8

    float bv[4];
#pragma unroll
    for (int cc = 0; cc < 4; ++cc) {
        int c = colw + cc * 16 + lm;
        bv[cc] = (c < HC) ? bias[c] : 0.f;
    }

    f32x4 acc[4][4];
#pragma unroll
    for (int m0 = 0; m0 < 4; ++m0)
#pragma unroll
        for (int cc = 0; cc < 4; ++cc) acc[m0][cc] = (f32x4){0.f, 0.f, 0.f, 0.f};

    // ---- feature GEMM with depth-2 weight prefetch ----
    bfrag8 bq[2][4];
#pragma unroll
    for (int cc = 0; cc < 4; ++cc)
        bq[0][cc] = *(const bfrag8*)(const void*)&W4[(size_t)((wv * 4 + cc) * KTS + 0) * 512 + lane8];
    if (KTS > 1) {
#pragma unroll
        for (int cc = 0; cc < 4; ++cc)
            bq[1][cc] = *(const bfrag8*)(const void*)&W4[(size_t)((wv * 4 + cc) * KTS + 1) * 512 + lane8];
    }
#pragma unroll
    for (int kt = 0; kt < KTS; ++kt) {
        bfrag8 a[4];
#pragma unroll
        for (int m0 = 0; m0 < 4; ++m0)
            a[m0] = *(const bfrag8*)(const void*)&cur[(m0 * 16 + lm) * 512 + ((kt * 32 + (lh << 3)) ^ kswz)];
        bfrag8 bc[4];
#pragma unroll
        for (int cc = 0; cc < 4; ++cc) bc[cc] = bq[kt & 1][cc];
        if (kt + 2 < KTS) {
#pragma unroll
            for (int cc = 0; cc < 4; ++cc)
                bq[kt & 1][cc] = *(const bfrag8*)(const void*)&W4[(size_t)((wv * 4 + cc) * KTS + kt + 2) * 512 + lane8];
        }
#pragma unroll
        for (int cc = 0; cc < 4; ++cc)
#pragma unroll
            for (int m0 = 0; m0 < 4; ++m0)
                acc[m0][cc] = __builtin_amdgcn_mfma_f32_16x16x32_bf16(a[m0], bc[cc], acc[m0][cc], 0, 0, 0);
    }
    __syncthreads();   // all waves' cur reads complete before epilogue rewrites cur

    // ---- write XW transposed (own cols) ----
#pragma unroll
    for (int cc = 0; cc < 4; ++cc) {
        const int c = colw + cc * 16 + lm;
#pragma unroll
        for (int m0 = 0; m0 < 4; ++m0) {
            const int rloc = m0 * 16 + (lh << 2);
            us4 p;
            p.a = f2b(acc[m0][cc][0]); p.b = f2b(acc[m0][cc][1]);
            p.c = f2b(acc[m0][cc][2]); p.d = f2b(acc[m0][cc][3]);
            *(us4*)(void*)&xwt[c * 72 + rloc] = p;
        }
    }

    // ---- adjacency: Y = A @ XW (hi/lo split), A frags from LDS ----
    bfrag8 ahf[4][2], alf[4][2];
#pragma unroll
    for (int m0 = 0; m0 < 4; ++m0)
#pragma unroll
        for (int kc = 0; kc < 2; ++kc) {
            int o = (m0 * 16 + lm) * 64 + kc * 32 + (lh << 3);
            ahf[m0][kc] = *(const bfrag8*)(const void*)&ahl[o];
            alf[m0][kc] = *(const bfrag8*)(const void*)&ahl[4096 + o];
        }
#pragma unroll
    for (int m0 = 0; m0 < 4; ++m0)
#pragma unroll
        for (int cc = 0; cc < 4; ++cc) acc[m0][cc] = (f32x4){0.f, 0.f, 0.f, 0.f};
#pragma unroll
    for (int cc = 0; cc < 4; ++cc) {
        const int c = colw + cc * 16 + lm;
        bfrag8 b0 = *(const bfrag8*)(const void*)&xwt[c * 72 + (lh << 3)];
        bfrag8 b1 = *(const bfrag8*)(const void*)&xwt[c * 72 + 32 + (lh << 3)];
#pragma unroll
        for (int m0 = 0; m0 < 4; ++m0) {
            acc[m0][cc] = __builtin_amdgcn_mfma_f32_16x16x32_bf16(ahf[m0][0], b0, acc[m0][cc], 0, 0, 0);
            acc[m0][cc] = __builtin_amdgcn_mfma_f32_16x16x32_bf16(alf[m0][0], b0, acc[m0][cc], 0, 0, 0);
            acc[m0][cc] = __builtin_amdgcn_mfma_f32_16x16x32_bf16(ahf[m0][1], b1, acc[m0][cc], 0, 0, 0);
            acc[m0][cc] = __builtin_amdgcn_mfma_f32_16x16x32_bf16(alf[m0][1], b1, acc[m0][cc], 0, 0, 0);
        }
    }

    // ---- bias + pool + Y -> cur (bf16) ----
#pragma unroll
    for (int cc = 0; cc < 4; ++cc) {
        const int c = colw + cc * 16 + lm;
        float cs = 0.f;
#pragma unroll
        for (int m0 = 0; m0 < 4; ++m0) {
            const int rb = m0 * 16 + (lh << 2);
#pragma unroll
            for (int r = 0; r < 4; ++r) {
                float v = acc[m0][cc][r] + bv[cc];
                cs += v;
                const int row = rb + r;
                cur[row * 512 + (c ^ ((row & 7) << 3))] = f2b(v);
            }
        }
        cs += __shfl_xor(cs, 16, 64);
        cs += __shfl_xor(cs, 32, 64);
        if (lh == 0 && c < HC) hsg[c] = cs * (1.0f / 64.0f);
    }
    __syncthreads();   // cur complete before next layer's feature reads
}

// ---------------------------------------------------------------------------
// Whole-GCN mega-kernel: one block = one graph, 8 waves, all 4 layers in LDS.
// ---------------------------------------------------------------------------
__global__ __launch_bounds__(512, 2) void gcn_all(const float* __restrict__ x,
                                                  const int* __restrict__ esrc,
                                                  const int* __restrict__ edst,
                                                  const unsigned short* __restrict__ Wt0,
                                                  const unsigned short* __restrict__ Wt123,
                                                  const float* __restrict__ bg0,
                                                  const float* __restrict__ bgR,
                                                  float* __restrict__ hs)
{
    extern __shared__ char lds[];
    unsigned short* cur = (unsigned short*)lds;                    // 65536 B
    unsigned short* xwt = (unsigned short*)(lds + 65536);          // 73728 B
    unsigned short* ahl = (unsigned short*)(lds + 65536 + 73728);  // 16384 B
    float* Af   = (float*)(lds + 65536);                           // scratch in xwt
    int*   cnt  = (int*)(lds + 65536 + 16384);
    float* dinv = (float*)(lds + 65536 + 16384 + 256);

    const int g = blockIdx.x, tid = threadIdx.x;
    const int wv = tid >> 6, lane = tid & 63;
    const int lm = lane & 15, lh = lane >> 4;

    // ---- build normalized adjacency in LDS ----
    for (int i = tid; i < 4096; i += 512) Af[i] = 0.f;
    if (tid < 64) cnt[tid] = 0;
    __syncthreads();
    for (int e = tid; e < EPER; e += 512)
        atomicAdd(&cnt[edst[(size_t)g * EPER + e] & 63], 1);
    __syncthreads();
    if (tid < 64) dinv[tid] = rsqrtf((float)cnt[tid] + 1.0f);
    __syncthreads();
    for (int e = tid; e < EPER; e += 512) {
        int s = esrc[(size_t)g * EPER + e] & 63;
        int d = edst[(size_t)g * EPER + e] & 63;
        atomicAdd(&Af[d * 64 + s], dinv[s] * dinv[d]);
    }
    __syncthreads();
    if (tid < 64) Af[tid * 64 + tid] += dinv[tid] * dinv[tid];
    __syncthreads();
    for (int i = tid; i < 4096; i += 512) {
        float v = Af[i];
        unsigned short h = f2b(v);
        ahl[i] = h;
        ahl[4096 + i] = f2b(v - b2f(h));
    }
    // ---- load x -> cur (bf16, swizzled); layer0 uses k<64 only ----
    for (int i = tid; i < 1024; i += 512) {
        float4 v = ((const float4*)(x + (size_t)g * 4096))[i];
        int row = (i * 4) >> 6, col = (i * 4) & 63;
        unsigned short* p = &cur[row * 512 + (col ^ ((row & 7) << 3))];
        p[0] = f2b(v.x); p[1] = f2b(v.y); p[2] = f2b(v.z); p[3] = f2b(v.w);
    }
    __syncthreads();

    float* hsg = hs + (size_t)g * (HC * NLAY);
    gcn_layer<64>(Wt0, bg0, cur, xwt, ahl, hsg, wv, lm, lh);
    for (int l = 1; l < NLAY; ++l)
        gcn_layer<512>(Wt123 + (size_t)(l - 1) * 262144, bgR + (l - 1) * HC,
                       cur, xwt, ahl, hsg + l * HC, wv, lm, lh);
}

// ---------------------------------------------------------------------------
// BN statistics, stage 1: partial sums over a row block (coalesced).
// ---------------------------------------------------------------------------
__global__ __launch_bounds__(256) void stats_part(const float* __restrict__ in,
                                                  float* __restrict__ ps,
                                                  float* __restrict__ pss,
                                                  int F, int rpb)
{
    int f = blockIdx.x * 256 + threadIdx.x;
    if (f >= F) return;
    int r0 = blockIdx.y * rpb;
    float s = 0.f, ss = 0.f;
    for (int r = r0; r < r0 + rpb; ++r) {
        float v = in[(size_t)r * F + f];
        s += v; ss += v * v;
    }
    ps [(size_t)blockIdx.y * F + f] = s;
    pss[(size_t)blockIdx.y * F + f] = ss;
}

// ---------------------------------------------------------------------------
// BN statistics, stage 2: reduce GB partials -> mean, rsqrt(var+eps)
// ---------------------------------------------------------------------------
__global__ __launch_bounds__(256) void stats_fin(const float* __restrict__ ps,
                                                 const float* __restrict__ pss,
                                                 float* __restrict__ mean,
                                                 float* __restrict__ inv,
                                                 int F, int GB, float invR)
{
    int f = blockIdx.x * 256 + threadIdx.x;
    if (f >= F) return;
    float s = 0.f, ss = 0.f;
    for (int b = 0; b < GB; ++b) { s += ps[(size_t)b * F + f]; ss += pss[(size_t)b * F + f]; }
    float m = s * invR;
    mean[f] = m;
    inv[f]  = rsqrtf(ss * invR - m * m + 1e-5f);
}

// ---------------------------------------------------------------------------
// Gather triu entries of x into xv[g][t] + partial stats over 16 graphs.
// ---------------------------------------------------------------------------
__global__ __launch_bounds__(256) void xv_gather(const float* __restrict__ x,
                                                 const int* __restrict__ off,
                                                 float* __restrict__ xv,
                                                 float* __restrict__ ps,
                                                 float* __restrict__ pss)
{
    int t = blockIdx.x * 256 + threadIdx.x;
    if (t >= NTRIU) return;
    int o = off[t];
    int g0 = blockIdx.y * 16;
    float s = 0.f, ss = 0.f;
    for (int g = g0; g < g0 + 16; ++g) {
        float v = x[(size_t)g * 4096 + o];
        xv[(size_t)g * NTRIU + t] = v;
        s += v; ss += v * v;
    }
    ps [(size_t)blockIdx.y * NTRIU + t] = s;
    pss[(size_t)blockIdx.y * NTRIU + t] = ss;
}

// ---------------------------------------------------------------------------
// Fused: normalize xv & hs inline, attention dot, sigmoid, write z as
// split-bf16 (hi/lo) planes. One block per graph.
// ---------------------------------------------------------------------------
__global__ __launch_bounds__(256) void attz_fused(const float* __restrict__ xv,
                                                  const float* __restrict__ xm,
                                                  const float* __restrict__ xi,
                                                  const float* __restrict__ gx,
                                                  const float* __restrict__ bx,
                                                  const float* __restrict__ hsrc,
                                                  const float* __restrict__ hm,
                                                  const float* __restrict__ hi,
                                                  const float* __restrict__ gh,
                                                  const float* __restrict__ bh,
                                                  const float* __restrict__ Watt,
                                                  const float* __restrict__ batt,
                                                  unsigned short* __restrict__ zhi,
                                                  unsigned short* __restrict__ zlo)
{
    int g = blockIdx.x;
    __shared__ float xs[NTRIU];
    __shared__ float red[256];
    float s = 0.f;
    for (int t = threadIdx.x; t < NTRIU; t += 256) {
        float v = (xv[(size_t)g * NTRIU + t] - xm[t]) * xi[t] * gx[t] + bx[t];
        xs[t] = v;
        s += v * Watt[t];
    }
    red[threadIdx.x] = s;
    __syncthreads();
    for (int w = 128; w > 0; w >>= 1) {
        if (threadIdx.x < w) red[threadIdx.x] += red[threadIdx.x + w];
        __syncthreads();
    }
    float att = 1.0f / (1.0f + expf(-(red[0] + batt[0])));
    for (int t = threadIdx.x; t < NTRIU; t += 256) {
        float hn = (hsrc[(size_t)g * NTRIU + t] - hm[t]) * hi[t] * gh[t] + bh[t];
        float zf = att * xs[t] + (1.0f - att) * hn * 0.5f;
        unsigned short h0 = f2b(zf);
        zhi[(size_t)g * DCAT + t] = h0;
        zlo[(size_t)g * DCAT + t] = f2b(zf - b2f(h0));
        unsigned short h1 = f2b(hn);
        zhi[(size_t)g * DCAT + NTRIU + t] = h1;
        zlo[(size_t)g * DCAT + NTRIU + t] = f2b(hn - b2f(h1));
    }
}

// ---------------------------------------------------------------------------
// Split-K bf16 MFMA GEMM with hi/lo-split A:
// P[z][256][N] partial = (Ahi+Alo)[256][K-chunk] @ Bt[N][K]^T
// ---------------------------------------------------------------------------
__global__ __launch_bounds__(256) void gemm_bf_sk(const unsigned short* __restrict__ Ahi,
                                                  const unsigned short* __restrict__ Alo,
                                                  const unsigned short* __restrict__ Bt,
                                                  float* __restrict__ P,
                                                  int N, int K, int chunk)
{
    __shared__ unsigned short Ah[2][2048], Al[2][2048], Bs[2][2048];
    const int tid  = threadIdx.x;
    const int wave = tid >> 6, lane = tid & 63;
    const int row0 = blockIdx.y << 6, col0 = blockIdx.x << 6;
    const int kb = blockIdx.z * chunk;
    const int NT = chunk >> 5;
    const int sr = tid >> 2, sk = (tid & 3) << 3;
    const unsigned short* gAh = Ahi + (size_t)(row0 + sr) * K + kb + sk;
    const unsigned short* gAl = Alo + (size_t)(row0 + sr) * K + kb + sk;
    const unsigned short* gB  = Bt  + (size_t)(col0 + sr) * K + kb + sk;

    int4 rh = *(const int4*)(const void*)gAh;
    int4 rl = *(const int4*)(const void*)gAl;
    int4 rb = *(const int4*)(const void*)gB;
    *(int4*)(void*)&Ah[0][tid << 3] = rh;
    *(int4*)(void*)&Al[0][tid << 3] = rl;
    *(int4*)(void*)&Bs[0][tid << 3] = rb;
    __syncthreads();

    f32x4 acc0 = {0.f, 0.f, 0.f, 0.f};
    f32x4 acc1 = acc0, acc2 = acc0, acc3 = acc0;
    const int aoff = (wave * 16 + (lane & 15)) * 32 + ((lane >> 4) << 3);
    const int boff = (lane & 15) * 32 + ((lane >> 4) << 3);

    for (int t = 0; t < NT; ++t) {
        if (t + 1 < NT) {
            rh = *(const int4*)(const void*)(gAh + (t + 1) * 32);
            rl = *(const int4*)(const void*)(gAl + (t + 1) * 32);
            rb = *(const int4*)(const void*)(gB  + (t + 1) * 32);
        }
        const unsigned short* ah = Ah[t & 1];
        const unsigned short* al = Al[t & 1];
        const unsigned short* bs = Bs[t & 1];
        bfrag8 a  = *(const bfrag8*)(const void*)&ah[aoff];
        bfrag8 a2 = *(const bfrag8*)(const void*)&al[aoff];
        bfrag8 b0 = *(const bfrag8*)(const void*)&bs[boff];
        bfrag8 b1 = *(const bfrag8*)(const void*)&bs[boff + 16 * 32];
        bfrag8 b2 = *(const bfrag8*)(const void*)&bs[boff + 32 * 32];
        bfrag8 b3 = *(const bfrag8*)(const void*)&bs[boff + 48 * 32];
        acc0 = __builtin_amdgcn_mfma_f32_16x16x32_bf16(a,  b0, acc0, 0, 0, 0);
        acc0 = __builtin_amdgcn_mfma_f32_16x16x32_bf16(a2, b0, acc0, 0, 0, 0);
        acc1 = __builtin_amdgcn_mfma_f32_16x16x32_bf16(a,  b1, acc1, 0, 0, 0);
        acc1 = __builtin_amdgcn_mfma_f32_16x16x32_bf16(a2, b1, acc1, 0, 0, 0);
        acc2 = __builtin_amdgcn_mfma_f32_16x16x32_bf16(a,  b2, acc2, 0, 0, 0);
        acc2 = __builtin_amdgcn_mfma_f32_16x16x32_bf16(a2, b2, acc2, 0, 0, 0);
        acc3 = __builtin_amdgcn_mfma_f32_16x16x32_bf16(a,  b3, acc3, 0, 0, 0);
        acc3 = __builtin_amdgcn_mfma_f32_16x16x32_bf16(a2, b3, acc3, 0, 0, 0);
        if (t + 1 < NT) {
            *(int4*)(void*)&Ah[(t + 1) & 1][tid << 3] = rh;
            *(int4*)(void*)&Al[(t + 1) & 1][tid << 3] = rl;
            *(int4*)(void*)&Bs[(t + 1) & 1][tid << 3] = rb;
        }
        __syncthreads();
    }

    float* Pp = P + (size_t)blockIdx.z * NGRAPH * N;
    const int rbase = row0 + wave * 16 + ((lane >> 4) << 2);
    const int cbase = col0 + (lane & 15);
#pragma unroll
    for (int r = 0; r < 4; ++r) {
        int grow = rbase + r;
        Pp[(size_t)grow * N + cbase +  0] = acc0[r];
        Pp[(size_t)grow * N + cbase + 16] = acc1[r];
        Pp[(size_t)grow * N + cbase + 32] = acc2[r];
        Pp[(size_t)grow * N + cbase + 48] = acc3[r];
    }
}

// ---------------------------------------------------------------------------
// Fused MLP post: split-K reduce + bias -> LDS, full BN stats, apply + ReLU,
// emit split-bf16 hi/lo. One block = 32 features x all 256 rows.
// ---------------------------------------------------------------------------
__global__ __launch_bounds__(256) void mlp_post(const float* __restrict__ P,
                                                const float* __restrict__ bias,
                                                const float* __restrict__ gamma,
                                                const float* __restrict__ beta,
                                                unsigned short* __restrict__ hi,
                                                unsigned short* __restrict__ lo,
                                                int N, int S)
{
    __shared__ float vals[NGRAPH][32];
    __shared__ float rs[8][32], rss[8][32];
    __shared__ float smean[32], sinv[32];
    const int tf = threadIdx.x & 31, tr = threadIdx.x >> 5;
    const int f = blockIdx.x * 32 + tf;
    const size_t MN = (size_t)NGRAPH * N;
    float bv = bias[f];
    float s = 0.f, ss = 0.f;
    for (int r = tr * 32; r < tr * 32 + 32; ++r) {
        float v = 0.f;
        for (int t = 0; t < S; ++t) v += P[(size_t)t * MN + (size_t)r * N + f];
        v += bv;
        vals[r][tf] = v;
        s += v; ss += v * v;
    }
    rs[tr][tf] = s; rss[tr][tf] = ss;
    __syncthreads();
    if (tr == 0) {
        float S1 = 0.f, S2 = 0.f;
#pragma unroll
        for (int b = 0; b < 8; ++b) { S1 += rs[b][tf]; S2 += rss[b][tf]; }
        float m = S1 * (1.0f / NGRAPH);
        smean[tf] = m;
        sinv[tf] = rsqrtf(S2 * (1.0f / NGRAPH) - m * m + 1e-5f);
    }
    __syncthreads();
    const float m = smean[tf], iv = sinv[tf] * gamma[f], bt = beta[f];
    for (int r = tr * 32; r < tr * 32 + 32; ++r) {
        float v = (vals[r][tf] - m) * iv + bt;
        v = fmaxf(v, 0.f);
        unsigned short h0 = f2b(v);
        hi[(size_t)r * N + f] = h0;
        lo[(size_t)r * N + f] = f2b(v - b2f(h0));
    }
}

// ---------------------------------------------------------------------------
// Final tiny linear from hi/lo bf16: out[g][0:2] = m3[g] @ Wm4 + bm4
// ---------------------------------------------------------------------------
__global__ __launch_bounds__(256) void final_kernel(const unsigned short* __restrict__ Xhi,
                                                    const unsigned short* __restrict__ Xlo,
                                                    const float* __restrict__ W,
                                                    const float* __restrict__ b,
                                                    float* __restrict__ out)
{
    int g = blockIdx.x;
    float s0 = 0.f, s1 = 0.f;
    for (int k = threadIdx.x; k < HID2; k += 256) {
        float v = b2f(Xhi[(size_t)g * HID2 + k]) + b2f(Xlo[(size_t)g * HID2 + k]);
        s0 += v * W[k * 2 + 0];
        s1 += v * W[k * 2 + 1];
    }
    __shared__ float r0[256], r1[256];
    r0[threadIdx.x] = s0; r1[threadIdx.x] = s1;
    __syncthreads();
    for (int w = 128; w > 0; w >>= 1) {
        if (threadIdx.x < w) {
            r0[threadIdx.x] += r0[threadIdx.x + w];
            r1[threadIdx.x] += r1[threadIdx.x + w];
        }
        __syncthreads();
    }
    if (threadIdx.x == 0) {
        out[g * 2 + 0] = r0[0] + b[0];
        out[g * 2 + 1] = r1[0] + b[1];
    }
}

// ---------------------------------------------------------------------------
extern "C" void kernel_launch(void* const* d_in, const int* in_sizes, int n_in,
                              void* d_out, int out_size, void* d_ws, size_t ws_size,
                              hipStream_t stream)
{
    const float* x      = (const float*)d_in[0];
    const float* Wg0    = (const float*)d_in[1];
    const float* bg0    = (const float*)d_in[2];
    const float* WgR    = (const float*)d_in[3];
    const float* bgR    = (const float*)d_in[4];
    const float* gx     = (const float*)d_in[5];
    const float* bx     = (const float*)d_in[6];
    const float* gh     = (const float*)d_in[7];
    const float* bh     = (const float*)d_in[8];
    const float* Watt   = (const float*)d_in[9];
    const float* batt   = (const float*)d_in[10];
    const float* Wm1    = (const float*)d_in[11];
    const float* bm1    = (const float*)d_in[12];
    const float* gm1    = (const float*)d_in[13];
    const float* bem1   = (const float*)d_in[14];
    const float* Wm2    = (const float*)d_in[15];
    const float* bm2    = (const float*)d_in[16];
    const float* gm2    = (const float*)d_in[17];
    const float* bem2   = (const float*)d_in[18];
    const float* Wm3    = (const float*)d_in[19];
    const float* bm3    = (const float*)d_in[20];
    const float* gm3    = (const float*)d_in[21];
    const float* bem3   = (const float*)d_in[22];
    const float* Wm4    = (const float*)d_in[23];
    const float* bm4    = (const float*)d_in[24];
    const int*   esrc   = (const int*)d_in[25];
    const int*   edst   = (const int*)d_in[26];
    float* out = (float*)d_out;

    char* w = (char*)d_ws;
    auto alloc = [&](size_t bytes) -> char* {
        char* p = w;
        w += (bytes + 255) & ~(size_t)255;
        return p;
    };
    unsigned short* Wt0   = (unsigned short*)alloc((size_t)512 * 64 * 2);
    unsigned short* Wt123 = (unsigned short*)alloc((size_t)3 * 512 * 512 * 2);
    unsigned short* W1t   = (unsigned short*)alloc((size_t)HID1 * DCAT * 2);
    unsigned short* W2t   = (unsigned short*)alloc((size_t)HID2 * HID1 * 2);
    unsigned short* W3t   = (unsigned short*)alloc((size_t)HID2 * HID2 * 2);
    float*          hs    = (float*)alloc((size_t)NGRAPH * NTRIU * 4);
    float*          xv    = (float*)alloc((size_t)NGRAPH * NTRIU * 4);
    unsigned short* zhi   = (unsigned short*)alloc((size_t)NGRAPH * DCAT * 2);
    unsigned short* zlo   = (unsigned short*)alloc((size_t)NGRAPH * DCAT * 2);
    float*          P     = (float*)alloc((size_t)8 * NGRAPH * HID1 * 4);
    unsigned short* m1hi  = (unsigned short*)alloc((size_t)NGRAPH * HID1 * 2);
    unsigned short* m1lo  = (unsigned short*)alloc((size_t)NGRAPH * HID1 * 2);
    unsigned short* m2hi  = (unsigned short*)alloc((size_t)NGRAPH * HID2 * 2);
    unsigned short* m2lo  = (unsigned short*)alloc((size_t)NGRAPH * HID2 * 2);
    unsigned short* m3hi  = (unsigned short*)alloc((size_t)NGRAPH * HID2 * 2);
    unsigned short* m3lo  = (unsigned short*)alloc((size_t)NGRAPH * HID2 * 2);
    float*          ps    = (float*)alloc((size_t)16 * NTRIU * 4);
    float*          pss   = (float*)alloc((size_t)16 * NTRIU * 4);
    float*          xm    = (float*)alloc(NTRIU * 4);
    float*          xi    = (float*)alloc(NTRIU * 4);
    float*          hm    = (float*)alloc(NTRIU * 4);
    float*          hiv   = (float*)alloc(NTRIU * 4);
    int*            off   = (int*)alloc(NTRIU * 4);

    hipFuncSetAttribute((const void*)gcn_all,
                        hipFuncAttributeMaxDynamicSharedMemorySize, GCN_LDS);

    triu_off<<<1, 64, 0, stream>>>(off);
    convW4<<<dim3(16, 2, 1),   dim3(32, 8), 0, stream>>>(Wg0, Wt0, 64, HC, 64, 0, 0);
    convW4<<<dim3(16, 16, 3),  dim3(32, 8), 0, stream>>>(WgR, Wt123, HC, HC, 512,
                                                         (long long)HC * HC, 512LL * 512);
    convWt<<<dim3(32, 126, 1), dim3(32, 8), 0, stream>>>(Wm1, W1t, DCAT, HID1, DCAT, 0, 0);
    convWt<<<dim3(16, 32, 1),  dim3(32, 8), 0, stream>>>(Wm2, W2t, HID1, HID2, HID1, 0, 0);
    convWt<<<dim3(16, 16, 1),  dim3(32, 8), 0, stream>>>(Wm3, W3t, HID2, HID2, HID2, 0, 0);

    // Whole GCN (adjacency build + 4 layers + pool) in one kernel, 8 waves
    gcn_all<<<NGRAPH, 512, GCN_LDS, stream>>>(x, esrc, edst, Wt0, Wt123, bg0, bgR, hs);

    // BN stats for h and xv, fused attention + z (split-bf16)
    stats_part<<<dim3(8, 16), 256, 0, stream>>>(hs, ps, pss, NTRIU, 16);
    stats_fin<<<8, 256, 0, stream>>>(ps, pss, hm, hiv, NTRIU, 16, 1.0f / NGRAPH);
    xv_gather<<<dim3(8, 16), 256, 0, stream>>>(x, off, xv, ps, pss);
    stats_fin<<<8, 256, 0, stream>>>(ps, pss, xm, xi, NTRIU, 16, 1.0f / NGRAPH);
    attz_fused<<<NGRAPH, 256, 0, stream>>>(xv, xm, xi, gx, bx, hs, hm, hiv, gh, bh,
                                           Watt, batt, zhi, zlo);

    // MLP layer 1: [256,4032] @ [4032,1024]
    gemm_bf_sk<<<dim3(16, 4, 7), 256, 0, stream>>>(zhi, zlo, W1t, P, HID1, DCAT, 576);
    mlp_post<<<32, 256, 0, stream>>>(P, bm1, gm1, bem1, m1hi, m1lo, HID1, 7);

    // MLP layer 2: [256,1024] @ [1024,512]
    gemm_bf_sk<<<dim3(8, 4, 8), 256, 0, stream>>>(m1hi, m1lo, W2t, P, HID2, HID1, 128);
    mlp_post<<<16, 256, 0, stream>>>(P, bm2, gm2, bem2, m2hi, m2lo, HID2, 8);

    // MLP layer 3: [256,512] @ [512,512]
    gemm_bf_sk<<<dim3(8, 4, 8), 256, 0, stream>>>(m2hi, m2lo, W3t, P, HID2, HID2, 64);
    mlp_post<<<16, 256, 0, stream>>>(P, bm3, gm3, bem3, m3hi, m3lo, HID2, 8);

    final_kernel<<<NGRAPH, 256, 0, stream>>>(m3hi, m3lo, Wm4, bm4, out);
}

// Round 7
// 175.853 us; speedup vs baseline: 1.8761x; 1.8761x over previous
//
#include <hip/hip_runtime.h>
#include <math.h>

#define NGRAPH 256
#define NPG 64
#define NFEAT 64
#define HC 504
#define NLAY 4
#define EPER 1024
#define NTRIU 2016
#define DCAT 4032
#define HID1 1024
#define HID2 512

#define GCN_LDS (65536 + 73728 + 16384)   // cur + xwt + ahl = 155648 B

typedef __attribute__((ext_vector_type(8))) short bfrag8;   // 8 bf16 in 4 VGPRs
typedef __attribute__((ext_vector_type(4))) float f32x4;

struct __align__(8) us4 { unsigned short a, b, c, d; };

__device__ __forceinline__ unsigned short f2b(float f) {
    union { float f; unsigned u; } v; v.f = f;
    unsigned r = (v.u + 0x7fffu + ((v.u >> 16) & 1u)) >> 16;   // RNE
    return (unsigned short)r;
}
__device__ __forceinline__ float b2f(unsigned short h) {
    union { unsigned u; float f; } v; v.u = ((unsigned)h) << 16;
    return v.f;
}

// ---------------------------------------------------------------------------
// triu(64, k=1) flat-offset table: off[t] = iu*64 + ju
// ---------------------------------------------------------------------------
__global__ void triu_off(int* __restrict__ off)
{
    int i = threadIdx.x;
    if (i >= 63) return;
    int o = 63 * i - i * (i - 1) / 2;
    for (int j = i + 1; j < 64; ++j) { off[o] = i * 64 + j; ++o; }
}

// ---------------------------------------------------------------------------
// Weight transpose+convert (row layout): Wt[n][k] = bf16(W[k][n])
// ---------------------------------------------------------------------------
__global__ void convWt(const float* __restrict__ W, unsigned short* __restrict__ Wt,
                       int K, int N, int KP, long long sStride, long long dStride)
{
    W  += (size_t)blockIdx.z * sStride;
    Wt += (size_t)blockIdx.z * dStride;
    __shared__ float T[32][33];
    int k0 = blockIdx.y * 32, n0 = blockIdx.x * 32;
    int tx = threadIdx.x, ty = threadIdx.y;
#pragma unroll
    for (int j = 0; j < 32; j += 8) {
        int k = k0 + ty + j, n = n0 + tx;
        T[ty + j][tx] = (k < K && n < N) ? W[(size_t)k * N + n] : 0.f;
    }
    __syncthreads();
#pragma unroll
    for (int j = 0; j < 32; j += 8) {
        int n = n0 + ty + j, k = k0 + tx;
        Wt[(size_t)n * KP + k] = f2b(T[tx][ty + j]);
    }
}

// ---------------------------------------------------------------------------
// Weight convert to MFMA-fragment-major layout (for gcn_all):
// elem (n,k) -> ((n>>4)*(KL/32) + (k>>5))*512 + ((k>>3)&3)*128 + (n&15)*8 + (k&7)
// ---------------------------------------------------------------------------
__global__ void convW4(const float* __restrict__ W, unsigned short* __restrict__ W4,
                       int K, int N, int KL, long long sStride, long long dStride)
{
    W  += (size_t)blockIdx.z * sStride;
    W4 += (size_t)blockIdx.z * dStride;
    __shared__ float T[32][33];
    int k0 = blockIdx.y * 32, n0 = blockIdx.x * 32;
    int tx = threadIdx.x, ty = threadIdx.y;
#pragma unroll
    for (int j = 0; j < 32; j += 8) {
        int k = k0 + ty + j, n = n0 + tx;
        T[ty + j][tx] = (k < K && n < N) ? W[(size_t)k * N + n] : 0.f;
    }
    __syncthreads();
#pragma unroll
    for (int j = 0; j < 32; j += 8) {
        int n = n0 + ty + j, k = k0 + tx;
        int idx = ((n >> 4) * (KL >> 5) + (k >> 5)) * 512
                + (((k >> 3) & 3) << 7) + ((n & 15) << 3) + (k & 7);
        W4[idx] = f2b(T[tx][ty + j]);
    }
}

// ---------------------------------------------------------------------------
// One GCN layer for one graph (8 waves, wave wv owns cols wv*64..wv*64+63).
// ---------------------------------------------------------------------------
template<int KL>
__device__ __forceinline__ void gcn_layer(const unsigned short* __restrict__ W4,
                                          const float* __restrict__ bias,
                                          unsigned short* cur, unsigned short* xwt,
                                          const unsigned short* ahl,
                                          float* __restrict__ hsg,
                                          int wv, int lm, int lh)
{
    constexpr int KTS = KL >> 5;
    const int colw = wv << 6;
    const int kswz = (lm & 7) << 3;
    const int lane8 = ((lh << 4) + lm) << 3;   // lane * 8

    float bv[4];
#pragma unroll
    for (int cc = 0; cc < 4; ++cc) {
        int c = colw + cc * 16 + lm;
        bv[cc] = (c < HC) ? bias[c] : 0.f;
    }

    f32x4 acc[4][4];
#pragma unroll
    for (int m0 = 0; m0 < 4; ++m0)
#pragma unroll
        for (int cc = 0; cc < 4; ++cc) acc[m0][cc] = (f32x4){0.f, 0.f, 0.f, 0.f};

    // ---- feature GEMM with depth-2 weight prefetch ----
    bfrag8 bq[2][4];
#pragma unroll
    for (int cc = 0; cc < 4; ++cc)
        bq[0][cc] = *(const bfrag8*)(const void*)&W4[(size_t)((wv * 4 + cc) * KTS + 0) * 512 + lane8];
    if (KTS > 1) {
#pragma unroll
        for (int cc = 0; cc < 4; ++cc)
            bq[1][cc] = *(const bfrag8*)(const void*)&W4[(size_t)((wv * 4 + cc) * KTS + 1) * 512 + lane8];
    }
#pragma unroll
    for (int kt = 0; kt < KTS; ++kt) {
        bfrag8 a[4];
#pragma unroll
        for (int m0 = 0; m0 < 4; ++m0)
            a[m0] = *(const bfrag8*)(const void*)&cur[(m0 * 16 + lm) * 512 + ((kt * 32 + (lh << 3)) ^ kswz)];
        bfrag8 bc[4];
#pragma unroll
        for (int cc = 0; cc < 4; ++cc) bc[cc] = bq[kt & 1][cc];
        if (kt + 2 < KTS) {
#pragma unroll
            for (int cc = 0; cc < 4; ++cc)
                bq[kt & 1][cc] = *(const bfrag8*)(const void*)&W4[(size_t)((wv * 4 + cc) * KTS + kt + 2) * 512 + lane8];
        }
#pragma unroll
        for (int cc = 0; cc < 4; ++cc)
#pragma unroll
            for (int m0 = 0; m0 < 4; ++m0)
                acc[m0][cc] = __builtin_amdgcn_mfma_f32_16x16x32_bf16(a[m0], bc[cc], acc[m0][cc], 0, 0, 0);
    }
    __syncthreads();   // all waves' cur reads complete before epilogue rewrites cur

    // ---- write XW transposed (own cols) ----
#pragma unroll
    for (int cc = 0; cc < 4; ++cc) {
        const int c = colw + cc * 16 + lm;
#pragma unroll
        for (int m0 = 0; m0 < 4; ++m0) {
            const int rloc = m0 * 16 + (lh << 2);
            us4 p;
            p.a = f2b(acc[m0][cc][0]); p.b = f2b(acc[m0][cc][1]);
            p.c = f2b(acc[m0][cc][2]); p.d = f2b(acc[m0][cc][3]);
            *(us4*)(void*)&xwt[c * 72 + rloc] = p;
        }
    }

    // ---- adjacency: Y = A @ XW (hi/lo split), A frags from LDS ----
    bfrag8 ahf[4][2], alf[4][2];
#pragma unroll
    for (int m0 = 0; m0 < 4; ++m0)
#pragma unroll
        for (int kc = 0; kc < 2; ++kc) {
            int o = (m0 * 16 + lm) * 64 + kc * 32 + (lh << 3);
            ahf[m0][kc] = *(const bfrag8*)(const void*)&ahl[o];
            alf[m0][kc] = *(const bfrag8*)(const void*)&ahl[4096 + o];
        }
#pragma unroll
    for (int m0 = 0; m0 < 4; ++m0)
#pragma unroll
        for (int cc = 0; cc < 4; ++cc) acc[m0][cc] = (f32x4){0.f, 0.f, 0.f, 0.f};
#pragma unroll
    for (int cc = 0; cc < 4; ++cc) {
        const int c = colw + cc * 16 + lm;
        bfrag8 b0 = *(const bfrag8*)(const void*)&xwt[c * 72 + (lh << 3)];
        bfrag8 b1 = *(const bfrag8*)(const void*)&xwt[c * 72 + 32 + (lh << 3)];
#pragma unroll
        for (int m0 = 0; m0 < 4; ++m0) {
            acc[m0][cc] = __builtin_amdgcn_mfma_f32_16x16x32_bf16(ahf[m0][0], b0, acc[m0][cc], 0, 0, 0);
            acc[m0][cc] = __builtin_amdgcn_mfma_f32_16x16x32_bf16(alf[m0][0], b0, acc[m0][cc], 0, 0, 0);
            acc[m0][cc] = __builtin_amdgcn_mfma_f32_16x16x32_bf16(ahf[m0][1], b1, acc[m0][cc], 0, 0, 0);
            acc[m0][cc] = __builtin_amdgcn_mfma_f32_16x16x32_bf16(alf[m0][1], b1, acc[m0][cc], 0, 0, 0);
        }
    }

    // ---- bias + pool + Y -> cur (bf16) ----
#pragma unroll
    for (int cc = 0; cc < 4; ++cc) {
        const int c = colw + cc * 16 + lm;
        float cs = 0.f;
#pragma unroll
        for (int m0 = 0; m0 < 4; ++m0) {
            const int rb = m0 * 16 + (lh << 2);
#pragma unroll
            for (int r = 0; r < 4; ++r) {
                float v = acc[m0][cc][r] + bv[cc];
                cs += v;
                const int row = rb + r;
                cur[row * 512 + (c ^ ((row & 7) << 3))] = f2b(v);
            }
        }
        cs += __shfl_xor(cs, 16, 64);
        cs += __shfl_xor(cs, 32, 64);
        if (lh == 0 && c < HC) hsg[c] = cs * (1.0f / 64.0f);
    }
    __syncthreads();   // cur complete before next layer's feature reads
}

// ---------------------------------------------------------------------------
// Whole-GCN mega-kernel: one block = one graph, 8 waves, all 4 layers in LDS.
// ---------------------------------------------------------------------------
__global__ __launch_bounds__(512, 2) void gcn_all(const float* __restrict__ x,
                                                  const int* __restrict__ esrc,
                                                  const int* __restrict__ edst,
                                                  const unsigned short* __restrict__ Wt0,
                                                  const unsigned short* __restrict__ Wt123,
                                                  const float* __restrict__ bg0,
                                                  const float* __restrict__ bgR,
                                                  float* __restrict__ hs)
{
    extern __shared__ char lds[];
    unsigned short* cur = (unsigned short*)lds;                    // 65536 B
    unsigned short* xwt = (unsigned short*)(lds + 65536);          // 73728 B
    unsigned short* ahl = (unsigned short*)(lds + 65536 + 73728);  // 16384 B
    float* Af   = (float*)(lds + 65536);                           // scratch in xwt
    int*   cnt  = (int*)(lds + 65536 + 16384);
    float* dinv = (float*)(lds + 65536 + 16384 + 256);

    const int g = blockIdx.x, tid = threadIdx.x;
    const int wv = tid >> 6, lane = tid & 63;
    const int lm = lane & 15, lh = lane >> 4;

    // ---- build normalized adjacency in LDS ----
    for (int i = tid; i < 4096; i += 512) Af[i] = 0.f;
    if (tid < 64) cnt[tid] = 0;
    __syncthreads();
    for (int e = tid; e < EPER; e += 512)
        atomicAdd(&cnt[edst[(size_t)g * EPER + e] & 63], 1);
    __syncthreads();
    if (tid < 64) dinv[tid] = rsqrtf((float)cnt[tid] + 1.0f);
    __syncthreads();
    for (int e = tid; e < EPER; e += 512) {
        int s = esrc[(size_t)g * EPER + e] & 63;
        int d = edst[(size_t)g * EPER + e] & 63;
        atomicAdd(&Af[d * 64 + s], dinv[s] * dinv[d]);
    }
    __syncthreads();
    if (tid < 64) Af[tid * 64 + tid] += dinv[tid] * dinv[tid];
    __syncthreads();
    for (int i = tid; i < 4096; i += 512) {
        float v = Af[i];
        unsigned short h = f2b(v);
        ahl[i] = h;
        ahl[4096 + i] = f2b(v - b2f(h));
    }
    // ---- load x -> cur (bf16, swizzled); layer0 uses k<64 only ----
    for (int i = tid; i < 1024; i += 512) {
        float4 v = ((const float4*)(x + (size_t)g * 4096))[i];
        int row = (i * 4) >> 6, col = (i * 4) & 63;
        unsigned short* p = &cur[row * 512 + (col ^ ((row & 7) << 3))];
        p[0] = f2b(v.x); p[1] = f2b(v.y); p[2] = f2b(v.z); p[3] = f2b(v.w);
    }
    __syncthreads();

    float* hsg = hs + (size_t)g * (HC * NLAY);
    gcn_layer<64>(Wt0, bg0, cur, xwt, ahl, hsg, wv, lm, lh);
    for (int l = 1; l < NLAY; ++l)
        gcn_layer<512>(Wt123 + (size_t)(l - 1) * 262144, bgR + (l - 1) * HC,
                       cur, xwt, ahl, hsg + l * HC, wv, lm, lh);
}

// ---------------------------------------------------------------------------
// BN statistics, stage 1: partial sums over a row block (coalesced).
// ---------------------------------------------------------------------------
__global__ __launch_bounds__(256) void stats_part(const float* __restrict__ in,
                                                  float* __restrict__ ps,
                                                  float* __restrict__ pss,
                                                  int F, int rpb)
{
    int f = blockIdx.x * 256 + threadIdx.x;
    if (f >= F) return;
    int r0 = blockIdx.y * rpb;
    float s = 0.f, ss = 0.f;
    for (int r = r0; r < r0 + rpb; ++r) {
        float v = in[(size_t)r * F + f];
        s += v; ss += v * v;
    }
    ps [(size_t)blockIdx.y * F + f] = s;
    pss[(size_t)blockIdx.y * F + f] = ss;
}

// ---------------------------------------------------------------------------
// BN statistics, stage 2: reduce GB partials -> mean, rsqrt(var+eps)
// ---------------------------------------------------------------------------
__global__ __launch_bounds__(256) void stats_fin(const float* __restrict__ ps,
                                                 const float* __restrict__ pss,
                                                 float* __restrict__ mean,
                                                 float* __restrict__ inv,
                                                 int F, int GB, float invR)
{
    int f = blockIdx.x * 256 + threadIdx.x;
    if (f >= F) return;
    float s = 0.f, ss = 0.f;
    for (int b = 0; b < GB; ++b) { s += ps[(size_t)b * F + f]; ss += pss[(size_t)b * F + f]; }
    float m = s * invR;
    mean[f] = m;
    inv[f]  = rsqrtf(ss * invR - m * m + 1e-5f);
}

// ---------------------------------------------------------------------------
// Gather triu entries of x into xv[g][t] + partial stats over 16 graphs.
// ---------------------------------------------------------------------------
__global__ __launch_bounds__(256) void xv_gather(const float* __restrict__ x,
                                                 const int* __restrict__ off,
                                                 float* __restrict__ xv,
                                                 float* __restrict__ ps,
                                                 float* __restrict__ pss)
{
    int t = blockIdx.x * 256 + threadIdx.x;
    if (t >= NTRIU) return;
    int o = off[t];
    int g0 = blockIdx.y * 16;
    float s = 0.f, ss = 0.f;
    for (int g = g0; g < g0 + 16; ++g) {
        float v = x[(size_t)g * 4096 + o];
        xv[(size_t)g * NTRIU + t] = v;
        s += v; ss += v * v;
    }
    ps [(size_t)blockIdx.y * NTRIU + t] = s;
    pss[(size_t)blockIdx.y * NTRIU + t] = ss;
}

// ---------------------------------------------------------------------------
// Fused: normalize xv & hs inline, attention dot, sigmoid, write z as
// split-bf16 (hi/lo) planes. One block per graph.
// ---------------------------------------------------------------------------
__global__ __launch_bounds__(256) void attz_fused(const float* __restrict__ xv,
                                                  const float* __restrict__ xm,
                                                  const float* __restrict__ xi,
                                                  const float* __restrict__ gx,
                                                  const float* __restrict__ bx,
                                                  const float* __restrict__ hsrc,
                                                  const float* __restrict__ hm,
                                                  const float* __restrict__ hi,
                                                  const float* __restrict__ gh,
                                                  const float* __restrict__ bh,
                                                  const float* __restrict__ Watt,
                                                  const float* __restrict__ batt,
                                                  unsigned short* __restrict__ zhi,
                                                  unsigned short* __restrict__ zlo)
{
    int g = blockIdx.x;
    __shared__ float xs[NTRIU];
    __shared__ float red[256];
    float s = 0.f;
    for (int t = threadIdx.x; t < NTRIU; t += 256) {
        float v = (xv[(size_t)g * NTRIU + t] - xm[t]) * xi[t] * gx[t] + bx[t];
        xs[t] = v;
        s += v * Watt[t];
    }
    red[threadIdx.x] = s;
    __syncthreads();
    for (int w = 128; w > 0; w >>= 1) {
        if (threadIdx.x < w) red[threadIdx.x] += red[threadIdx.x + w];
        __syncthreads();
    }
    float att = 1.0f / (1.0f + expf(-(red[0] + batt[0])));
    for (int t = threadIdx.x; t < NTRIU; t += 256) {
        float hn = (hsrc[(size_t)g * NTRIU + t] - hm[t]) * hi[t] * gh[t] + bh[t];
        float zf = att * xs[t] + (1.0f - att) * hn * 0.5f;
        unsigned short h0 = f2b(zf);
        zhi[(size_t)g * DCAT + t] = h0;
        zlo[(size_t)g * DCAT + t] = f2b(zf - b2f(h0));
        unsigned short h1 = f2b(hn);
        zhi[(size_t)g * DCAT + NTRIU + t] = h1;
        zlo[(size_t)g * DCAT + NTRIU + t] = f2b(hn - b2f(h1));
    }
}

// ---------------------------------------------------------------------------
// Split-K bf16 MFMA GEMM with hi/lo-split A:
// P[z][256][N] partial = (Ahi+Alo)[256][K-chunk] @ Bt[N][K]^T
// ---------------------------------------------------------------------------
__global__ __launch_bounds__(256) void gemm_bf_sk(const unsigned short* __restrict__ Ahi,
                                                  const unsigned short* __restrict__ Alo,
                                                  const unsigned short* __restrict__ Bt,
                                                  float* __restrict__ P,
                                                  int N, int K, int chunk)
{
    __shared__ unsigned short Ah[2][2048], Al[2][2048], Bs[2][2048];
    const int tid  = threadIdx.x;
    const int wave = tid >> 6, lane = tid & 63;
    const int row0 = blockIdx.y << 6, col0 = blockIdx.x << 6;
    const int kb = blockIdx.z * chunk;
    const int NT = chunk >> 5;
    const int sr = tid >> 2, sk = (tid & 3) << 3;
    const unsigned short* gAh = Ahi + (size_t)(row0 + sr) * K + kb + sk;
    const unsigned short* gAl = Alo + (size_t)(row0 + sr) * K + kb + sk;
    const unsigned short* gB  = Bt  + (size_t)(col0 + sr) * K + kb + sk;

    int4 rh = *(const int4*)(const void*)gAh;
    int4 rl = *(const int4*)(const void*)gAl;
    int4 rb = *(const int4*)(const void*)gB;
    *(int4*)(void*)&Ah[0][tid << 3] = rh;
    *(int4*)(void*)&Al[0][tid << 3] = rl;
    *(int4*)(void*)&Bs[0][tid << 3] = rb;
    __syncthreads();

    f32x4 acc0 = {0.f, 0.f, 0.f, 0.f};
    f32x4 acc1 = acc0, acc2 = acc0, acc3 = acc0;
    const int aoff = (wave * 16 + (lane & 15)) * 32 + ((lane >> 4) << 3);
    const int boff = (lane & 15) * 32 + ((lane >> 4) << 3);

    for (int t = 0; t < NT; ++t) {
        if (t + 1 < NT) {
            rh = *(const int4*)(const void*)(gAh + (t + 1) * 32);
            rl = *(const int4*)(const void*)(gAl + (t + 1) * 32);
            rb = *(const int4*)(const void*)(gB  + (t + 1) * 32);
        }
        const unsigned short* ah = Ah[t & 1];
        const unsigned short* al = Al[t & 1];
        const unsigned short* bs = Bs[t & 1];
        bfrag8 a  = *(const bfrag8*)(const void*)&ah[aoff];
        bfrag8 a2 = *(const bfrag8*)(const void*)&al[aoff];
        bfrag8 b0 = *(const bfrag8*)(const void*)&bs[boff];
        bfrag8 b1 = *(const bfrag8*)(const void*)&bs[boff + 16 * 32];
        bfrag8 b2 = *(const bfrag8*)(const void*)&bs[boff + 32 * 32];
        bfrag8 b3 = *(const bfrag8*)(const void*)&bs[boff + 48 * 32];
        acc0 = __builtin_amdgcn_mfma_f32_16x16x32_bf16(a,  b0, acc0, 0, 0, 0);
        acc0 = __builtin_amdgcn_mfma_f32_16x16x32_bf16(a2, b0, acc0, 0, 0, 0);
        acc1 = __builtin_amdgcn_mfma_f32_16x16x32_bf16(a,  b1, acc1, 0, 0, 0);
        acc1 = __builtin_amdgcn_mfma_f32_16x16x32_bf16(a2, b1, acc1, 0, 0, 0);
        acc2 = __builtin_amdgcn_mfma_f32_16x16x32_bf16(a,  b2, acc2, 0, 0, 0);
        acc2 = __builtin_amdgcn_mfma_f32_16x16x32_bf16(a2, b2, acc2, 0, 0, 0);
        acc3 = __builtin_amdgcn_mfma_f32_16x16x32_bf16(a,  b3, acc3, 0, 0, 0);
        acc3 = __builtin_amdgcn_mfma_f32_16x16x32_bf16(a2, b3, acc3, 0, 0, 0);
        if (t + 1 < NT) {
            *(int4*)(void*)&Ah[(t + 1) & 1][tid << 3] = rh;
            *(int4*)(void*)&Al[(t + 1) & 1][tid << 3] = rl;
            *(int4*)(void*)&Bs[(t + 1) & 1][tid << 3] = rb;
        }
        __syncthreads();
    }

    float* Pp = P + (size_t)blockIdx.z * NGRAPH * N;
    const int rbase = row0 + wave * 16 + ((lane >> 4) << 2);
    const int cbase = col0 + (lane & 15);
#pragma unroll
    for (int r = 0; r < 4; ++r) {
        int grow = rbase + r;
        Pp[(size_t)grow * N + cbase +  0] = acc0[r];
        Pp[(size_t)grow * N + cbase + 16] = acc1[r];
        Pp[(size_t)grow * N + cbase + 32] = acc2[r];
        Pp[(size_t)grow * N + cbase + 48] = acc3[r];
    }
}

// ---------------------------------------------------------------------------
// Sum S split-K partials + bias -> mf. Nmask = N-1 (N power of two).
// One thread per output element; partial loads fully coalesced.
// ---------------------------------------------------------------------------
__global__ __launch_bounds__(256) void reduce_add(const float* __restrict__ P,
                                                  const float* __restrict__ bias,
                                                  float* __restrict__ C, int MN,
                                                  int Nmask, int S)
{
    int i = blockIdx.x * 256 + threadIdx.x;
    if (i >= MN) return;
    float s = 0.f;
    for (int t = 0; t < S; ++t) s += P[(size_t)t * MN + i];
    C[i] = s + bias[i & Nmask];
}

// ---------------------------------------------------------------------------
// BN apply + ReLU -> split-bf16 hi/lo planes.
// ---------------------------------------------------------------------------
__global__ __launch_bounds__(256) void bn_apply_bf(const float* __restrict__ M_,
                                                   const float* __restrict__ mean,
                                                   const float* __restrict__ inv,
                                                   const float* __restrict__ gamma,
                                                   const float* __restrict__ beta,
                                                   unsigned short* __restrict__ hi,
                                                   unsigned short* __restrict__ lo,
                                                   int total, int mask)
{
    int i = blockIdx.x * 256 + threadIdx.x;
    if (i >= total) return;
    int f = i & mask;
    float v = (M_[i] - mean[f]) * inv[f] * gamma[f] + beta[f];
    v = fmaxf(v, 0.f);
    unsigned short h = f2b(v);
    hi[i] = h;
    lo[i] = f2b(v - b2f(h));
}

// ---------------------------------------------------------------------------
// Final tiny linear from hi/lo bf16: out[g][0:2] = m3[g] @ Wm4 + bm4
// ---------------------------------------------------------------------------
__global__ __launch_bounds__(256) void final_kernel(const unsigned short* __restrict__ Xhi,
                                                    const unsigned short* __restrict__ Xlo,
                                                    const float* __restrict__ W,
                                                    const float* __restrict__ b,
                                                    float* __restrict__ out)
{
    int g = blockIdx.x;
    float s0 = 0.f, s1 = 0.f;
    for (int k = threadIdx.x; k < HID2; k += 256) {
        float v = b2f(Xhi[(size_t)g * HID2 + k]) + b2f(Xlo[(size_t)g * HID2 + k]);
        s0 += v * W[k * 2 + 0];
        s1 += v * W[k * 2 + 1];
    }
    __shared__ float r0[256], r1[256];
    r0[threadIdx.x] = s0; r1[threadIdx.x] = s1;
    __syncthreads();
    for (int w = 128; w > 0; w >>= 1) {
        if (threadIdx.x < w) {
            r0[threadIdx.x] += r0[threadIdx.x + w];
            r1[threadIdx.x] += r1[threadIdx.x + w];
        }
        __syncthreads();
    }
    if (threadIdx.x == 0) {
        out[g * 2 + 0] = r0[0] + b[0];
        out[g * 2 + 1] = r1[0] + b[1];
    }
}

// ---------------------------------------------------------------------------
extern "C" void kernel_launch(void* const* d_in, const int* in_sizes, int n_in,
                              void* d_out, int out_size, void* d_ws, size_t ws_size,
                              hipStream_t stream)
{
    const float* x      = (const float*)d_in[0];
    const float* Wg0    = (const float*)d_in[1];
    const float* bg0    = (const float*)d_in[2];
    const float* WgR    = (const float*)d_in[3];
    const float* bgR    = (const float*)d_in[4];
    const float* gx     = (const float*)d_in[5];
    const float* bx     = (const float*)d_in[6];
    const float* gh     = (const float*)d_in[7];
    const float* bh     = (const float*)d_in[8];
    const float* Watt   = (const float*)d_in[9];
    const float* batt   = (const float*)d_in[10];
    const float* Wm1    = (const float*)d_in[11];
    const float* bm1    = (const float*)d_in[12];
    const float* gm1    = (const float*)d_in[13];
    const float* bem1   = (const float*)d_in[14];
    const float* Wm2    = (const float*)d_in[15];
    const float* bm2    = (const float*)d_in[16];
    const float* gm2    = (const float*)d_in[17];
    const float* bem2   = (const float*)d_in[18];
    const float* Wm3    = (const float*)d_in[19];
    const float* bm3    = (const float*)d_in[20];
    const float* gm3    = (const float*)d_in[21];
    const float* bem3   = (const float*)d_in[22];
    const float* Wm4    = (const float*)d_in[23];
    const float* bm4    = (const float*)d_in[24];
    const int*   esrc   = (const int*)d_in[25];
    const int*   edst   = (const int*)d_in[26];
    float* out = (float*)d_out;

    char* w = (char*)d_ws;
    auto alloc = [&](size_t bytes) -> char* {
        char* p = w;
        w += (bytes + 255) & ~(size_t)255;
        return p;
    };
    unsigned short* Wt0   = (unsigned short*)alloc((size_t)512 * 64 * 2);
    unsigned short* Wt123 = (unsigned short*)alloc((size_t)3 * 512 * 512 * 2);
    unsigned short* W1t   = (unsigned short*)alloc((size_t)HID1 * DCAT * 2);
    unsigned short* W2t   = (unsigned short*)alloc((size_t)HID2 * HID1 * 2);
    unsigned short* W3t   = (unsigned short*)alloc((size_t)HID2 * HID2 * 2);
    float*          hs    = (float*)alloc((size_t)NGRAPH * NTRIU * 4);
    float*          xv    = (float*)alloc((size_t)NGRAPH * NTRIU * 4);
    unsigned short* zhi   = (unsigned short*)alloc((size_t)NGRAPH * DCAT * 2);
    unsigned short* zlo   = (unsigned short*)alloc((size_t)NGRAPH * DCAT * 2);
    float*          P     = (float*)alloc((size_t)8 * NGRAPH * HID1 * 4);
    float*          mf    = (float*)alloc((size_t)NGRAPH * HID1 * 4);
    unsigned short* m1hi  = (unsigned short*)alloc((size_t)NGRAPH * HID1 * 2);
    unsigned short* m1lo  = (unsigned short*)alloc((size_t)NGRAPH * HID1 * 2);
    unsigned short* m2hi  = (unsigned short*)alloc((size_t)NGRAPH * HID2 * 2);
    unsigned short* m2lo  = (unsigned short*)alloc((size_t)NGRAPH * HID2 * 2);
    unsigned short* m3hi  = (unsigned short*)alloc((size_t)NGRAPH * HID2 * 2);
    unsigned short* m3lo  = (unsigned short*)alloc((size_t)NGRAPH * HID2 * 2);
    float*          ps    = (float*)alloc((size_t)16 * NTRIU * 4);
    float*          pss   = (float*)alloc((size_t)16 * NTRIU * 4);
    float*          xm    = (float*)alloc(NTRIU * 4);
    float*          xi    = (float*)alloc(NTRIU * 4);
    float*          hm    = (float*)alloc(NTRIU * 4);
    float*          hiv   = (float*)alloc(NTRIU * 4);
    float*          mmean = (float*)alloc(HID1 * 4);
    float*          minv  = (float*)alloc(HID1 * 4);
    int*            off   = (int*)alloc(NTRIU * 4);

    hipFuncSetAttribute((const void*)gcn_all,
                        hipFuncAttributeMaxDynamicSharedMemorySize, GCN_LDS);

    triu_off<<<1, 64, 0, stream>>>(off);
    convW4<<<dim3(16, 2, 1),   dim3(32, 8), 0, stream>>>(Wg0, Wt0, 64, HC, 64, 0, 0);
    convW4<<<dim3(16, 16, 3),  dim3(32, 8), 0, stream>>>(WgR, Wt123, HC, HC, 512,
                                                         (long long)HC * HC, 512LL * 512);
    convWt<<<dim3(32, 126, 1), dim3(32, 8), 0, stream>>>(Wm1, W1t, DCAT, HID1, DCAT, 0, 0);
    convWt<<<dim3(16, 32, 1),  dim3(32, 8), 0, stream>>>(Wm2, W2t, HID1, HID2, HID1, 0, 0);
    convWt<<<dim3(16, 16, 1),  dim3(32, 8), 0, stream>>>(Wm3, W3t, HID2, HID2, HID2, 0, 0);

    // Whole GCN (adjacency build + 4 layers + pool) in one kernel, 8 waves
    gcn_all<<<NGRAPH, 512, GCN_LDS, stream>>>(x, esrc, edst, Wt0, Wt123, bg0, bgR, hs);

    // BN stats for h and xv, fused attention + z (split-bf16)
    stats_part<<<dim3(8, 16), 256, 0, stream>>>(hs, ps, pss, NTRIU, 16);
    stats_fin<<<8, 256, 0, stream>>>(ps, pss, hm, hiv, NTRIU, 16, 1.0f / NGRAPH);
    xv_gather<<<dim3(8, 16), 256, 0, stream>>>(x, off, xv, ps, pss);
    stats_fin<<<8, 256, 0, stream>>>(ps, pss, xm, xi, NTRIU, 16, 1.0f / NGRAPH);
    attz_fused<<<NGRAPH, 256, 0, stream>>>(xv, xm, xi, gx, bx, hs, hm, hiv, gh, bh,
                                           Watt, batt, zhi, zlo);

    // MLP layer 1: [256,4032] @ [4032,1024]
    gemm_bf_sk<<<dim3(16, 4, 7), 256, 0, stream>>>(zhi, zlo, W1t, P, HID1, DCAT, 576);
    reduce_add<<<1024, 256, 0, stream>>>(P, bm1, mf, NGRAPH * HID1, HID1 - 1, 7);
    stats_part<<<dim3(4, 16), 256, 0, stream>>>(mf, ps, pss, HID1, 16);
    stats_fin<<<4, 256, 0, stream>>>(ps, pss, mmean, minv, HID1, 16, 1.0f / NGRAPH);
    bn_apply_bf<<<1024, 256, 0, stream>>>(mf, mmean, minv, gm1, bem1, m1hi, m1lo,
                                          NGRAPH * HID1, HID1 - 1);

    // MLP layer 2: [256,1024] @ [1024,512]
    gemm_bf_sk<<<dim3(8, 4, 8), 256, 0, stream>>>(m1hi, m1lo, W2t, P, HID2, HID1, 128);
    reduce_add<<<512, 256, 0, stream>>>(P, bm2, mf, NGRAPH * HID2, HID2 - 1, 8);
    stats_part<<<dim3(2, 16), 256, 0, stream>>>(mf, ps, pss, HID2, 16);
    stats_fin<<<2, 256, 0, stream>>>(ps, pss, mmean, minv, HID2, 16, 1.0f / NGRAPH);
    bn_apply_bf<<<512, 256, 0, stream>>>(mf, mmean, minv, gm2, bem2, m2hi, m2lo,
                                         NGRAPH * HID2, HID2 - 1);

    // MLP layer 3: [256,512] @ [512,512]
    gemm_bf_sk<<<dim3(8, 4, 8), 256, 0, stream>>>(m2hi, m2lo, W3t, P, HID2, HID2, 64);
    reduce_add<<<512, 256, 0, stream>>>(P, bm3, mf, NGRAPH * HID2, HID2 - 1, 8);
    stats_part<<<dim3(2, 16), 256, 0, stream>>>(mf, ps, pss, HID2, 16);
    stats_fin<<<2, 256, 0, stream>>>(ps, pss, mmean, minv, HID2, 16, 1.0f / NGRAPH);
    bn_apply_bf<<<512, 256, 0, stream>>>(mf, mmean, minv, gm3, bem3, m3hi, m3lo,
                                         NGRAPH * HID2, HID2 - 1);

    final_kernel<<<NGRAPH, 256, 0, stream>>>(m3hi, m3lo, Wm4, bm4, out);
}